// Round 5
// baseline (378.462 us; speedup 1.0000x reference)
//
#include <hip/hip_runtime.h>

// Problem constants (from reference): FeatureT (8,128,256,256) f32, centerInit (2,128) f32
#define BB      8
#define CHN     128
#define NPIX    65536           // 256*256

// Output flat offsets (floats), concatenated in return order
#define OFF_CENTERS 0                       // [2,128]            = 256
#define OFF_LABELS  256                     // [8,1,256,256]      = 524288
#define OFF_ONEHOT  (256 + 524288)          // [8,2,256,256] raw  = 1048576
#define OFF_DISTS   (OFF_ONEHOT + 1048576)  // [8,2,256,256] raw  = 1048576
#define OFF_LABELT  (OFF_DISTS + 1048576)   // [8,1,256,256]      = 524288

typedef float fvec4 __attribute__((ext_vector_type(4)));   // nontemporal-store-able

// ---------------------------------------------------------------------------
// Pass 1: dists, labels, onehot for all 8 batches. 4 pixels per thread.
// Margin trick: dot0 accumulated fp32 (feeds dist0), margin = dot0-dot1
// accumulated fp64 (exact label sign; dist1 = dist0 + 0.5*margin).
// Double-buffered loads keep 8 float4 reads in flight across each compute
// block. Write-only outputs use nontemporal stores to keep L2 clean for
// center_pass's F[7] re-read.
// ---------------------------------------------------------------------------
struct CPack { float c0; float pad; double dc; };   // 16 B, ds_read_b128-able

__global__ __launch_bounds__(256) void main_pass(
    const float* __restrict__ F, const float* __restrict__ C, float* __restrict__ out)
{
    __shared__ CPack cp[CHN];
    const int t = threadIdx.x;
    if (t < 128) {
        float c0 = C[t], c1 = C[CHN + t];
        cp[t].c0 = c0;
        cp[t].pad = 0.0f;
        cp[t].dc = (double)c0 - (double)c1;
    }
    __syncthreads();

    const int tid = blockIdx.x * 256 + t;   // 0..131071
    const int b   = tid >> 14;              // 16384 threads per batch image
    const int p   = tid & 16383;            // float4 index within the image
    const int n0  = p << 2;

    const float4* __restrict__ Fb = (const float4*)(F + (size_t)b * CHN * NPIX);

    float  dot0[4] = {0.f, 0.f, 0.f, 0.f};      // fp32: feeds dist0 (thr 0.605)
    double m[4]    = {0.0, 0.0, 0.0, 0.0};      // fp64: exact label sign

    float4 xa[8], xb[8];
    #pragma unroll
    for (int j = 0; j < 8; ++j)
        xa[j] = Fb[j * (NPIX / 4) + p];     // prime buffer A (cb = 0)

    #pragma unroll
    for (int cb = 0; cb < CHN; cb += 8) {
        float4* cur = ((cb >> 3) & 1) ? xb : xa;   // static after full unroll
        float4* nxt = ((cb >> 3) & 1) ? xa : xb;
        if (cb + 8 < CHN) {
            #pragma unroll
            for (int j = 0; j < 8; ++j)
                nxt[j] = Fb[(cb + 8 + j) * (NPIX / 4) + p];   // prefetch next batch
        }
        #pragma unroll
        for (int j = 0; j < 8; ++j) {
            float  a0 = cp[cb + j].c0;
            double dc = cp[cb + j].dc;
            float x0 = cur[j].x, x1 = cur[j].y, x2 = cur[j].z, x3 = cur[j].w;
            dot0[0] = fmaf(x0, a0, dot0[0]);  m[0] = fma((double)x0, dc, m[0]);
            dot0[1] = fmaf(x1, a0, dot0[1]);  m[1] = fma((double)x1, dc, m[1]);
            dot0[2] = fmaf(x2, a0, dot0[2]);  m[2] = fma((double)x2, dc, m[2]);
            dot0[3] = fmaf(x3, a0, dot0[3]);  m[3] = fma((double)x3, dc, m[3]);
        }
    }

    float labf[4], dist0[4], dist1[4];
    #pragma unroll
    for (int j = 0; j < 4; ++j) {
        float dd0 = 0.5f * (1.0f - dot0[j]);
        // dd1 - dd0 = 0.5*(dot0 - dot1) = 0.5*m ; label=1 iff dd1<dd0 iff m<0
        int lab = (m[j] < 0.0) ? 1 : 0;          // exact sign, ties -> 0
        labf[j]  = (float)lab;
        dist0[j] = dd0;
        dist1[j] = (float)((double)dd0 + 0.5 * m[j]);
    }

    fvec4 lab4 = {labf[0], labf[1], labf[2], labf[3]};
    // labels are re-read by center_pass -> normal store; rest write-only -> nontemporal
    *(fvec4*)(out + OFF_LABELS + b * NPIX + n0) = lab4;
    __builtin_nontemporal_store(lab4, (fvec4*)(out + OFF_LABELT + b * NPIX + n0));

    const size_t obase = (size_t)OFF_ONEHOT + (size_t)b * (2 * NPIX) + 2 * n0;
    fvec4 oh0 = {1.0f - labf[0], labf[0], 1.0f - labf[1], labf[1]};
    fvec4 oh1 = {1.0f - labf[2], labf[2], 1.0f - labf[3], labf[3]};
    __builtin_nontemporal_store(oh0, (fvec4*)(out + obase));
    __builtin_nontemporal_store(oh1, (fvec4*)(out + obase + 4));

    const size_t dbase = (size_t)OFF_DISTS + (size_t)b * (2 * NPIX) + 2 * n0;
    fvec4 dv0 = {dist0[0], dist1[0], dist0[1], dist1[1]};
    fvec4 dv1 = {dist0[2], dist1[2], dist0[3], dist1[3]};
    __builtin_nontemporal_store(dv0, (fvec4*)(out + dbase));
    __builtin_nontemporal_store(dv1, (fvec4*)(out + dbase + 4));
}

// ---------------------------------------------------------------------------
// Pass 2 (fused sum+final): one 1024-thread block per channel (16 iterations).
// Reduces F[7][ch][:] masked by labels[7] (cache-hot) plus the class-1 count,
// then writes its two center outputs directly.
// ---------------------------------------------------------------------------
__global__ __launch_bounds__(1024) void center_pass(
    const float* __restrict__ F, const float* __restrict__ C, float* __restrict__ out)
{
    const int ch = blockIdx.x;          // 0..127
    const int t  = threadIdx.x;         // 0..1023

    const float4* __restrict__ Fc = (const float4*)(F + (size_t)(7 * CHN + ch) * NPIX);
    const float4* __restrict__ L  = (const float4*)(out + OFF_LABELS + 7 * NPIX);

    double s_all = 0.0, s1 = 0.0;
    float  cntf  = 0.0f;                // exact: integer counts << 2^24

    #pragma unroll
    for (int i = 0; i < 16; ++i) {      // NPIX/4 / 1024 = 16
        int idx = t + i * 1024;
        float4 x = Fc[idx];
        float4 l = L[idx];              // components exactly 0.0 or 1.0
        s_all += (double)x.x + (double)x.y + (double)x.z + (double)x.w;
        s1 += (double)(l.x * x.x) + (double)(l.y * x.y)
            + (double)(l.z * x.z) + (double)(l.w * x.w);
        cntf += l.x + l.y + l.z + l.w;
    }

    #pragma unroll
    for (int off = 32; off > 0; off >>= 1) {
        s_all += __shfl_down(s_all, off, 64);
        s1    += __shfl_down(s1,    off, 64);
        cntf  += __shfl_down(cntf,  off, 64);
    }

    __shared__ double redA[16], redS[16], redC[16];
    const int wave = t >> 6, lane = t & 63;
    if (lane == 0) { redA[wave] = s_all; redS[wave] = s1; redC[wave] = (double)cntf; }
    __syncthreads();
    if (t == 0) {
        double A = 0.0, S1 = 0.0, cnt1 = 0.0;
        #pragma unroll
        for (int w = 0; w < 16; ++w) { A += redA[w]; S1 += redS[w]; cnt1 += redC[w]; }
        double Num0 = ((double)NPIX - cnt1) + 1.0;
        double Num1 = cnt1 + 1.0;
        double ci0  = (A - S1) / Num0;           // class-0 masked mean
        double ci1  = S1 / Num1;                 // class-1 masked mean
        double c0   = (double)C[ch];
        double c1   = (double)C[CHN + ch];
        out[OFF_CENTERS + ch]       = (float)(c0 + 0.001 * (ci0 - c0));
        out[OFF_CENTERS + CHN + ch] = (float)(c1 + 0.001 * (ci1 - c1));
    }
}

extern "C" void kernel_launch(void* const* d_in, const int* in_sizes, int n_in,
                              void* d_out, int out_size, void* d_ws, size_t ws_size,
                              hipStream_t stream) {
    const float* F = (const float*)d_in[0];   // FeatureT (8,128,256,256)
    const float* C = (const float*)d_in[1];   // centerInit (2,128)
    float* out = (float*)d_out;

    main_pass<<<dim3(512), dim3(256), 0, stream>>>(F, C, out);
    center_pass<<<dim3(128), dim3(1024), 0, stream>>>(F, C, out);
}

// Round 6
// 369.131 us; speedup vs baseline: 1.0253x; 1.0253x over previous
//
#include <hip/hip_runtime.h>

// Problem constants (from reference): FeatureT (8,128,256,256) f32, centerInit (2,128) f32
#define BB      8
#define CHN     128
#define NPIX    65536           // 256*256

// Output flat offsets (floats), concatenated in return order
#define OFF_CENTERS 0                       // [2,128]            = 256
#define OFF_LABELS  256                     // [8,1,256,256]      = 524288
#define OFF_ONEHOT  (256 + 524288)          // [8,2,256,256] raw  = 1048576
#define OFF_DISTS   (OFF_ONEHOT + 1048576)  // [8,2,256,256] raw  = 1048576
#define OFF_LABELT  (OFF_DISTS + 1048576)   // [8,1,256,256]      = 524288

typedef float fvec2 __attribute__((ext_vector_type(2)));
typedef float fvec4 __attribute__((ext_vector_type(4)));

// ---------------------------------------------------------------------------
// Pass 1: dists, labels, onehot. 2 pixels per thread, 1024 blocks x 256 thr
// = 4 waves/SIMD (vs 2 before): per-wave vmcnt/dep-chain stalls get covered
// by sibling waves. float2 (8 B/lane) loads, double-buffered 8 deep.
// Channel-loop accumulation order identical to R5 -> bit-identical outputs.
// ---------------------------------------------------------------------------
struct CPack { float c0; float pad; double dc; };

__global__ __launch_bounds__(256) void main_pass(
    const float* __restrict__ F, const float* __restrict__ C, float* __restrict__ out)
{
    __shared__ CPack cp[CHN];
    const int t = threadIdx.x;
    if (t < 128) {
        float c0 = C[t], c1 = C[CHN + t];
        cp[t].c0 = c0;
        cp[t].pad = 0.0f;
        cp[t].dc = (double)c0 - (double)c1;
    }
    __syncthreads();

    const int tid = blockIdx.x * 256 + t;   // 0..262143
    const int b   = tid >> 15;              // 32768 threads per batch image
    const int p   = tid & 32767;            // float2 index within the image
    const int n0  = p << 1;                 // first pixel

    const float2* __restrict__ Fb = (const float2*)(F + (size_t)b * CHN * NPIX);

    float  dot0[2] = {0.f, 0.f};            // fp32: feeds dist0 (thr 0.605)
    double m[2]    = {0.0, 0.0};            // fp64: exact label sign

    float2 xa[8], xb[8];
    #pragma unroll
    for (int j = 0; j < 8; ++j)
        xa[j] = Fb[j * (NPIX / 2) + p];     // prime buffer A (cb = 0)

    #pragma unroll
    for (int cb = 0; cb < CHN; cb += 8) {
        float2* cur = ((cb >> 3) & 1) ? xb : xa;   // static after full unroll
        float2* nxt = ((cb >> 3) & 1) ? xa : xb;
        if (cb + 8 < CHN) {
            #pragma unroll
            for (int j = 0; j < 8; ++j)
                nxt[j] = Fb[(cb + 8 + j) * (NPIX / 2) + p];   // prefetch next batch
        }
        #pragma unroll
        for (int j = 0; j < 8; ++j) {
            float  a0 = cp[cb + j].c0;
            double dc = cp[cb + j].dc;
            float x0 = cur[j].x, x1 = cur[j].y;
            dot0[0] = fmaf(x0, a0, dot0[0]);  m[0] = fma((double)x0, dc, m[0]);
            dot0[1] = fmaf(x1, a0, dot0[1]);  m[1] = fma((double)x1, dc, m[1]);
        }
    }

    float labf[2], dist0[2], dist1[2];
    #pragma unroll
    for (int j = 0; j < 2; ++j) {
        float dd0 = 0.5f * (1.0f - dot0[j]);
        // dd1 - dd0 = 0.5*(dot0 - dot1) = 0.5*m ; label=1 iff m<0 (exact sign)
        int lab = (m[j] < 0.0) ? 1 : 0;
        labf[j]  = (float)lab;
        dist0[j] = dd0;
        dist1[j] = (float)((double)dd0 + 0.5 * m[j]);
    }

    fvec2 lab2 = {labf[0], labf[1]};
    // labels are re-read by center_pass -> normal store; rest write-only -> nontemporal
    *(fvec2*)(out + OFF_LABELS + b * NPIX + n0) = lab2;
    __builtin_nontemporal_store(lab2, (fvec2*)(out + OFF_LABELT + b * NPIX + n0));

    const size_t obase = (size_t)OFF_ONEHOT + (size_t)b * (2 * NPIX) + 2 * n0;
    fvec4 oh = {1.0f - labf[0], labf[0], 1.0f - labf[1], labf[1]};
    __builtin_nontemporal_store(oh, (fvec4*)(out + obase));

    const size_t dbase = (size_t)OFF_DISTS + (size_t)b * (2 * NPIX) + 2 * n0;
    fvec4 dv = {dist0[0], dist1[0], dist0[1], dist1[1]};
    __builtin_nontemporal_store(dv, (fvec4*)(out + dbase));
}

// ---------------------------------------------------------------------------
// Pass 2 (fused sum+final): one 1024-thread block per channel (16 iterations).
// Reduces F[7][ch][:] masked by labels[7] (cache-hot) plus the class-1 count,
// then writes its two center outputs directly.
// ---------------------------------------------------------------------------
__global__ __launch_bounds__(1024) void center_pass(
    const float* __restrict__ F, const float* __restrict__ C, float* __restrict__ out)
{
    const int ch = blockIdx.x;          // 0..127
    const int t  = threadIdx.x;         // 0..1023

    const float4* __restrict__ Fc = (const float4*)(F + (size_t)(7 * CHN + ch) * NPIX);
    const float4* __restrict__ L  = (const float4*)(out + OFF_LABELS + 7 * NPIX);

    double s_all = 0.0, s1 = 0.0;
    float  cntf  = 0.0f;                // exact: integer counts << 2^24

    #pragma unroll
    for (int i = 0; i < 16; ++i) {      // NPIX/4 / 1024 = 16
        int idx = t + i * 1024;
        float4 x = Fc[idx];
        float4 l = L[idx];              // components exactly 0.0 or 1.0
        s_all += (double)x.x + (double)x.y + (double)x.z + (double)x.w;
        s1 += (double)(l.x * x.x) + (double)(l.y * x.y)
            + (double)(l.z * x.z) + (double)(l.w * x.w);
        cntf += l.x + l.y + l.z + l.w;
    }

    #pragma unroll
    for (int off = 32; off > 0; off >>= 1) {
        s_all += __shfl_down(s_all, off, 64);
        s1    += __shfl_down(s1,    off, 64);
        cntf  += __shfl_down(cntf,  off, 64);
    }

    __shared__ double redA[16], redS[16], redC[16];
    const int wave = t >> 6, lane = t & 63;
    if (lane == 0) { redA[wave] = s_all; redS[wave] = s1; redC[wave] = (double)cntf; }
    __syncthreads();
    if (t == 0) {
        double A = 0.0, S1 = 0.0, cnt1 = 0.0;
        #pragma unroll
        for (int w = 0; w < 16; ++w) { A += redA[w]; S1 += redS[w]; cnt1 += redC[w]; }
        double Num0 = ((double)NPIX - cnt1) + 1.0;
        double Num1 = cnt1 + 1.0;
        double ci0  = (A - S1) / Num0;           // class-0 masked mean
        double ci1  = S1 / Num1;                 // class-1 masked mean
        double c0   = (double)C[ch];
        double c1   = (double)C[CHN + ch];
        out[OFF_CENTERS + ch]       = (float)(c0 + 0.001 * (ci0 - c0));
        out[OFF_CENTERS + CHN + ch] = (float)(c1 + 0.001 * (ci1 - c1));
    }
}

extern "C" void kernel_launch(void* const* d_in, const int* in_sizes, int n_in,
                              void* d_out, int out_size, void* d_ws, size_t ws_size,
                              hipStream_t stream) {
    const float* F = (const float*)d_in[0];   // FeatureT (8,128,256,256)
    const float* C = (const float*)d_in[1];   // centerInit (2,128)
    float* out = (float*)d_out;

    main_pass<<<dim3(1024), dim3(256), 0, stream>>>(F, C, out);
    center_pass<<<dim3(128), dim3(1024), 0, stream>>>(F, C, out);
}